// Round 1
// 525.932 us; speedup vs baseline: 1.0367x; 1.0367x over previous
//
#include <hip/hip_runtime.h>
#include <hip/hip_bf16.h>
#include <math.h>

#define B_     4
#define SEQ_   1024
#define D_     1024
#define H_     16
#define NE_    8
#define INTER_ 768
#define EPS_   1e-5f

typedef unsigned short u16;
typedef __attribute__((ext_vector_type(8))) short s8v;      // 8 bf16 - MFMA A/B frag (K=32)
typedef __attribute__((ext_vector_type(4))) short s4v;      // 4 bf16 - MFMA A/B frag (K=16)
typedef __attribute__((ext_vector_type(4))) float f4v;      // MFMA C/D frag
typedef __attribute__((ext_vector_type(4))) unsigned short u16x4;
typedef __attribute__((ext_vector_type(8))) unsigned short u16x8;

__device__ __forceinline__ u16 f2bf(float x) {
    union { float f; unsigned u; } c; c.f = x;
    unsigned r = (c.u + 0x7FFFu + ((c.u >> 16) & 1u)) >> 16;
    return (u16)r;
}
__device__ __forceinline__ float bf2f(u16 h) {
    union { unsigned u; float f; } c; c.u = ((unsigned)h) << 16;
    return c.f;
}
__device__ __forceinline__ unsigned pk2(float a, float b) {
    union { float f; unsigned u; } x, y; x.f = a; y.f = b;
    return ((x.u + 0x8000u) >> 16) | ((y.u + 0x8000u) & 0xffff0000u);
}

#define GLDS16(gp, lp) \
    __builtin_amdgcn_global_load_lds((const __attribute__((address_space(1))) unsigned int*)(gp), \
                                     (__attribute__((address_space(3))) unsigned int*)(lp), 16, 0, 0)

// ---------------- routing stage 1 + bf16 cast of hidden ----------------
__global__ void route1(const float* __restrict__ hidden, float* __restrict__ part,
                       u16* __restrict__ hb) {
    int b = blockIdx.x, ch = blockIdx.y, t = threadIdx.x;
    const float* xb = hidden + (size_t)b * SEQ_ * D_ + (size_t)ch * 32 * D_;
    u16* ho = hb + (size_t)b * SEQ_ * D_ + (size_t)ch * 32 * D_;
    float4 acc = make_float4(0.f, 0.f, 0.f, 0.f);
    for (int r = 0; r < 32; ++r) {
        float4 v = *(const float4*)&xb[(size_t)r * D_ + t * 4];
        acc.x += v.x; acc.y += v.y; acc.z += v.z; acc.w += v.w;
        u16x4 o = {f2bf(v.x), f2bf(v.y), f2bf(v.z), f2bf(v.w)};
        *(u16x4*)&ho[(size_t)r * D_ + t * 4] = o;
    }
    *(float4*)&part[((size_t)(b * 32 + ch)) * D_ + t * 4] = acc;
}

__global__ void route2(const float* __restrict__ part, const float* __restrict__ Wr,
                       const float* __restrict__ temp, float* __restrict__ out_logits,
                       int* __restrict__ flat_idx, float* __restrict__ flat_w) {
    __shared__ float col[1024];
    __shared__ float sm[8];
    int b = blockIdx.x, t = threadIdx.x;
    float4 s = make_float4(0.f, 0.f, 0.f, 0.f);
    for (int ch = 0; ch < 32; ++ch) {
        float4 v = *(const float4*)&part[((size_t)(b * 32 + ch)) * D_ + t * 4];
        s.x += v.x; s.y += v.y; s.z += v.z; s.w += v.w;
    }
    col[t * 4 + 0] = s.x * (1.f / 1024.f);
    col[t * 4 + 1] = s.y * (1.f / 1024.f);
    col[t * 4 + 2] = s.z * (1.f / 1024.f);
    col[t * 4 + 3] = s.w * (1.f / 1024.f);
    __syncthreads();
    int j = t >> 5, d0 = t & 31;
    float p = 0.f;
    for (int d = d0; d < 1024; d += 32) p += col[d] * Wr[j * 1024 + d];
    for (int off = 16; off >= 1; off >>= 1) p += __shfl_down(p, off, 32);
    if (d0 == 0) sm[j] = p;
    __syncthreads();
    if (t == 0) {
        float tc = temp[0];
        tc = fminf(fmaxf(tc, 0.1f), 10.0f);
        float lg[8];
        for (int jj = 0; jj < 8; ++jj) {
            lg[jj] = sm[jj] / tc;
            out_logits[b * 8 + jj] = lg[jj];
        }
        int i0 = 0; float v0 = lg[0];
        for (int jj = 1; jj < 8; ++jj) if (lg[jj] > v0) { v0 = lg[jj]; i0 = jj; }
        int i1 = -1; float v1 = -1e30f;
        for (int jj = 0; jj < 8; ++jj) if (jj != i0 && lg[jj] > v1) { v1 = lg[jj]; i1 = jj; }
        float e1 = expf(v1 - v0);
        flat_idx[2 * b]     = i0;
        flat_idx[2 * b + 1] = i1;
        flat_w[2 * b]       = 1.0f / (1.0f + e1);
        flat_w[2 * b + 1]   = e1 / (1.0f + e1);
    }
}

// ---------------- combined weight transpose+cast (all 4 weights, one dispatch) ----------------
// ranges: [0,6144) Wqkv (K1024,N3072) | [6144,8192) Wo (1024,1024)
//         [8192,11264) Wgu (1024,1536, gate/up interleave perm) | [11264,12800) Wd (768,1024)
// Blocks whose expert is not selected by routing exit early (weights never read).
__global__ __launch_bounds__(256) void wtrans_all(const float* __restrict__ Wqkv,
                                                  const float* __restrict__ Wo,
                                                  const float* __restrict__ Wgu,
                                                  const float* __restrict__ Wd,
                                                  u16* __restrict__ WqkvT, u16* __restrict__ WoT,
                                                  u16* __restrict__ WguT, u16* __restrict__ WdT,
                                                  const int* __restrict__ flat_idx) {
    int bid = blockIdx.x;
    const float* W; u16* Wt; int K, N, nx, gu = 0;
    if (bid < 6144)      { W = Wqkv; Wt = WqkvT; K = 1024; N = 3072; nx = 48; }
    else if (bid < 8192) { bid -= 6144;  W = Wo;  Wt = WoT;  K = 1024; N = 1024; nx = 16; }
    else if (bid < 11264){ bid -= 8192;  W = Wgu; Wt = WguT; K = 1024; N = 1536; nx = 24; gu = 1; }
    else                 { bid -= 11264; W = Wd;  Wt = WdT;  K = 768;  N = 1024; nx = 16; }
    int x = bid % nx; bid /= nx;
    int ny = K >> 6;
    int y = bid % ny;
    int e = bid / ny;

    bool used = false;
#pragma unroll
    for (int jj = 0; jj < 8; ++jj) used |= (flat_idx[jj] == e);
    if (!used) return;                       // block-uniform: e is uniform

    __shared__ float tile[64][65];
    int k0 = y * 64, n0 = x * 64;
    const float* Wp = W + (size_t)e * K * N;
    u16* Wtp = Wt + (size_t)e * K * N;
    int t = threadIdx.x;
    int kk = t >> 4, ns = t & 15;
#pragma unroll
    for (int p = 0; p < 4; ++p) {
        float4 v = *(const float4*)&Wp[(size_t)(k0 + kk + p * 16) * N + n0 + ns * 4];
        tile[kk + p * 16][ns * 4 + 0] = v.x;
        tile[kk + p * 16][ns * 4 + 1] = v.y;
        tile[kk + p * 16][ns * 4 + 2] = v.z;
        tile[kk + p * 16][ns * 4 + 3] = v.w;
    }
    __syncthreads();
    int nn = t >> 3, ks = t & 7;
#pragma unroll
    for (int p = 0; p < 2; ++p) {
        int n = n0 + nn + p * 32;
        int nd = n;
        if (gu) nd = (n < 768) ? ((n >> 4) << 5) + (n & 15)
                               : (((n - 768) >> 4) << 5) + 16 + (n & 15);
        u16x8 o;
#pragma unroll
        for (int jj = 0; jj < 8; ++jj) o[jj] = f2bf(tile[ks * 8 + jj][nn + p * 32]);
        *(u16x8*)&Wtp[(size_t)nd * K + k0 + ks * 8] = o;
    }
}

// ================= 256x256 / 8-wave / BK=64 double-buffered GEMM core =================
// LDS layout per buffer: [256 rows][8 segs of 8 bf16], stored seg ss holds data seg
// ss ^ (row & 7) (XOR swizzle applied via pre-swizzled GLOBAL source; LDS writes linear).
// Prefetch distance = 1 K-tile: loads for tile t+1 issue at the START of tile t's compute,
// so the vmcnt(0) drain inside the single per-tile __syncthreads waits on ~640-cycle-old loads.
#define STAGE256(Ap, Wp, Kv, kt, tbv)                                                     \
    {                                                                                     \
        const u16* ga_ = (Ap) + (size_t)(m0 + srow) * (Kv) + (kt) * 64 + segsw;           \
        const u16* gb_ = (Wp) + (size_t)(n0 + srow) * (Kv) + (kt) * 64 + segsw;           \
        _Pragma("unroll") for (int q_ = 0; q_ < 4; ++q_) {                                \
            GLDS16(ga_ + (size_t)(q_ * 64) * (Kv), As + (tbv) + q_ * 4096 + w * 512);     \
            GLDS16(gb_ + (size_t)(q_ * 64) * (Kv), Bs + (tbv) + q_ * 4096 + w * 512);     \
        }                                                                                 \
    }

#define COMPUTE256(tbv)                                                                   \
    _Pragma("unroll") for (int ks_ = 0; ks_ < 2; ++ks_) {                                 \
        s8v af_[8];                                                                       \
        int sgk_ = ks_ ? sg1 : sg0;                                                       \
        _Pragma("unroll") for (int m_ = 0; m_ < 8; ++m_)                                  \
            af_[m_] = *(const s8v*)&As[(tbv) + rdA + m_ * 1024 + sgk_];                   \
        _Pragma("unroll") for (int np_ = 0; np_ < 2; ++np_) {                             \
            s8v b0_ = *(const s8v*)&Bs[(tbv) + rdB + (np_ * 2) * 1024 + sgk_];            \
            s8v b1_ = *(const s8v*)&Bs[(tbv) + rdB + (np_ * 2 + 1) * 1024 + sgk_];        \
            __builtin_amdgcn_s_setprio(1);                                                \
            _Pragma("unroll") for (int m_ = 0; m_ < 8; ++m_) {                            \
                acc[m_][np_ * 2]     = __builtin_amdgcn_mfma_f32_16x16x32_bf16(af_[m_], b0_, acc[m_][np_ * 2], 0, 0, 0);     \
                acc[m_][np_ * 2 + 1] = __builtin_amdgcn_mfma_f32_16x16x32_bf16(af_[m_], b1_, acc[m_][np_ * 2 + 1], 0, 0, 0); \
            }                                                                             \
            __builtin_amdgcn_s_setprio(0);                                                \
        }                                                                                 \
    }

#define GEMM_CORE256(Ap, Wp, Kv)                                                          \
    __shared__ __align__(16) u16 As[2 * 256 * 64];                                        \
    __shared__ __align__(16) u16 Bs[2 * 256 * 64];                                        \
    int t = threadIdx.x, lane = t & 63, w = t >> 6;                                       \
    int g = lane >> 4, c = lane & 15;                                                     \
    int wr = w >> 2, wc = w & 3;                                                          \
    int srow = t >> 3;                                                                    \
    int segsw = ((t & 7) ^ (srow & 7)) * 8;                                               \
    int rdA = (wr * 128 + c) * 64;                                                        \
    int rdB = (wc * 64 + c) * 64;                                                         \
    int sg0 = (g ^ (c & 7)) * 8, sg1 = ((4 + g) ^ (c & 7)) * 8;                           \
    f4v acc[8][4];                                                                        \
    _Pragma("unroll") for (int m_ = 0; m_ < 8; ++m_)                                      \
        _Pragma("unroll") for (int n_ = 0; n_ < 4; ++n_) acc[m_][n_] = (f4v){0.f, 0.f, 0.f, 0.f}; \
    const int NT = (Kv) / 64;                                                             \
    STAGE256(Ap, Wp, Kv, 0, 0)                                                            \
    __syncthreads();                                                                      \
    int tb = 0;                                                                           \
    for (int kt_ = 0; kt_ < NT; ++kt_) {                                                  \
        if (kt_ + 1 < NT) { STAGE256(Ap, Wp, Kv, kt_ + 1, tb ^ 16384) }                   \
        COMPUTE256(tb)                                                                    \
        __syncthreads();                                                                  \
        tb ^= 16384;                                                                      \
    }

// ---------------- generic bf16 MFMA GEMM (bf16 C) ----------------
__global__ __launch_bounds__(512, 2) void gemm_bf16(const u16* __restrict__ Abase,
                                                    const u16* __restrict__ Wtbase,
                                                    u16* __restrict__ Cb,
                                                    const int* __restrict__ flat_idx,
                                                    int M, int N, int K, int aDiv) {
    int e = blockIdx.z;
    const u16* A  = Abase + (size_t)(e / aDiv) * M * K;
    const u16* Wt = Wtbase + (size_t)flat_idx[e] * N * K;
    int m0 = blockIdx.y * 256, n0 = blockIdx.x * 256;

    GEMM_CORE256(A, Wt, K)

    u16* C = Cb + (size_t)e * M * N;
    int rb = m0 + wr * 128 + g * 4;
    int cb = n0 + wc * 64 + c;
#pragma unroll
    for (int m = 0; m < 8; ++m)
#pragma unroll
        for (int n = 0; n < 4; ++n)
#pragma unroll
            for (int i = 0; i < 4; ++i)
                C[(size_t)(rb + m * 16 + i) * N + cb + n * 16] = f2bf(acc[m][n][i]);
}

// ---------------- qkv GEMM with fused RoPE/scale/split epilogue ----------------
__global__ __launch_bounds__(512, 2) void gemm_qkv(const u16* __restrict__ Abase,
                                                   const u16* __restrict__ Wtbase,
                                                   const int* __restrict__ flat_idx,
                                                   const float* __restrict__ cosb,
                                                   const float* __restrict__ sinb,
                                                   u16* __restrict__ Qb, u16* __restrict__ Kb,
                                                   u16* __restrict__ Vb) {
    const int K = 1024, N = 3072;
    int e = blockIdx.z;
    const u16* A  = Abase + (size_t)(e >> 1) * 1024 * K;
    const u16* Wt = Wtbase + (size_t)flat_idx[e] * N * K;
    int m0 = blockIdx.y * 256, n0 = blockIdx.x * 256;

    GEMM_CORE256(A, Wt, K)

    int col0 = n0 + wc * 64;                 // multiple of 64, whole wave in one q/k/v region
    int sb = m0 + wr * 128 + g * 4;
    if (col0 < 2048) {
        bool isq = col0 < 1024;
        u16* dst = isq ? Qb : Kb;
        int h = (col0 & 1023) >> 6;
        const float scl = isq ? 0.125f * 1.44269504f : 1.0f;
#pragma unroll
        for (int m = 0; m < 8; ++m)
#pragma unroll
            for (int i = 0; i < 4; ++i) {
                int s = sb + m * 16 + i;
                size_t ob = ((size_t)(e * 1024) + s) * 1024 + h * 64;
#pragma unroll
                for (int nj = 0; nj < 2; ++nj) {
                    int d = nj * 16 + c;
                    float x1 = acc[m][nj][i], x2 = acc[m][nj + 2][i];
                    float c1 = cosb[s * 64 + d],      s1 = sinb[s * 64 + d];
                    float c2 = cosb[s * 64 + d + 32], s2 = sinb[s * 64 + d + 32];
                    dst[ob + d]      = f2bf((x1 * c1 - x2 * s1) * scl);
                    dst[ob + d + 32] = f2bf((x2 * c2 + x1 * s2) * scl);
                }
            }
    } else {
        int vcol = col0 - 2048;
#pragma unroll
        for (int m = 0; m < 8; ++m)
#pragma unroll
            for (int n = 0; n < 4; ++n)
#pragma unroll
                for (int i = 0; i < 4; ++i)
                    Vb[((size_t)(e * 1024) + sb + m * 16 + i) * 1024 + vcol + n * 16 + c] = f2bf(acc[m][n][i]);
    }
}

// ---------------- Wgu GEMM (interleaved columns) + fused SiLU*up epilogue ----------------
__global__ __launch_bounds__(512, 2) void gemm_wgu_silu(const u16* __restrict__ Abase,
                                                        const u16* __restrict__ Wtbase,
                                                        u16* __restrict__ act,
                                                        const int* __restrict__ flat_idx) {
    const int K = 1024, N = 1536;
    int e = blockIdx.z;
    const u16* A  = Abase + (size_t)e * 1024 * K;
    const u16* Wt = Wtbase + (size_t)flat_idx[e] * N * K;
    int m0 = blockIdx.y * 256, n0 = blockIdx.x * 256;

    GEMM_CORE256(A, Wt, K)

    int col0 = n0 + wc * 64;
    int oc0 = (col0 >> 1) + c;               // act col for n pair (0,1); +16 for (2,3)
    int sb = m0 + wr * 128 + g * 4;
#pragma unroll
    for (int m = 0; m < 8; ++m)
#pragma unroll
        for (int i = 0; i < 4; ++i) {
            size_t rb = ((size_t)(e * 1024) + sb + m * 16 + i) * 768;
#pragma unroll
            for (int pr = 0; pr < 2; ++pr) {
                float gt = acc[m][pr * 2][i];
                float up = acc[m][pr * 2 + 1][i];
                act[rb + oc0 + pr * 16] = f2bf(gt / (1.f + __expf(-gt)) * up);
            }
        }
}

// ---------------- V transpose: Vb[e][s][d] -> Vtg[e][h][d=64][kv=1024] ----------------
__global__ __launch_bounds__(256) void vtrans(const u16* __restrict__ Vb, u16* __restrict__ Vtg) {
    __shared__ __align__(16) u16 tile[64 * 72];
    int s0 = blockIdx.x * 64;
    int eh = blockIdx.y;
    int e = eh >> 4, h = eh & 15;
    int t = threadIdx.x;
#pragma unroll
    for (int it = 0; it < 2; ++it) {
        int p = it * 256 + t;
        int sr = p >> 3, ds = p & 7;
        u16x8 v = *(const u16x8*)&Vb[((size_t)(e * 1024) + s0 + sr) * 1024 + h * 64 + ds * 8];
        *(u16x8*)&tile[sr * 72 + ds * 8] = v;
    }
    __syncthreads();
#pragma unroll
    for (int it = 0; it < 2; ++it) {
        int p = it * 256 + t;
        int d = p >> 3, ks = p & 7;
        u16x8 o;
#pragma unroll
        for (int jj = 0; jj < 8; ++jj) o[jj] = tile[(ks * 8 + jj) * 72 + d];
        *(u16x8*)&Vtg[((size_t)((e * 16 + h) * 64) + d) * 1024 + s0 + ks * 8] = o;
    }
}

// ---------------- MFMA flash attention (S^T = K Q^T; register P) ----------------
__global__ __launch_bounds__(256) void attn_mfma(const u16* __restrict__ Qb, const u16* __restrict__ Kb,
                                                 const u16* __restrict__ Vtg, u16* __restrict__ ctx) {
    __shared__ __align__(16) u16 Ks[64 * 64];
    __shared__ __align__(16) u16 Vt[64 * 64];
    int e = blockIdx.x, h = blockIdx.y, qt = blockIdx.z;
    int t = threadIdx.x, lane = t & 63, w = t >> 6;
    int g = lane >> 4, c = lane & 15;
    int q0 = qt * 64 + w * 16;

    s8v qf[2];
#pragma unroll
    for (int ks = 0; ks < 2; ++ks)
        qf[ks] = *(const s8v*)&Qb[((size_t)(e * 1024) + q0 + c) * 1024 + h * 64 + ks * 32 + g * 8];

    f4v O[4];
#pragma unroll
    for (int tj = 0; tj < 4; ++tj) O[tj] = (f4v){0.f, 0.f, 0.f, 0.f};
    f4v liacc = (f4v){0.f, 0.f, 0.f, 0.f};
    const s4v vone = {(short)0x3F80, (short)0x3F80, (short)0x3F80, (short)0x3F80};

    for (int kt = 0; kt < 16; ++kt) {
#pragma unroll
        for (int it = 0; it < 2; ++it) {
            int p = it * 256 + w * 64 + lane;
            int row = p >> 3, ss = p & 7;
            GLDS16(Kb + ((size_t)(e * 1024 + kt * 64 + row)) * 1024 + h * 64 + (ss ^ (row & 7)) * 8,
                   Ks + (size_t)(it * 256 + w * 64) * 8);
            GLDS16(Vtg + ((size_t)((e * 16 + h) * 64 + row)) * 1024 + kt * 64 + (ss ^ (row & 7)) * 8,
                   Vt + (size_t)(it * 256 + w * 64) * 8);
        }
        __syncthreads();

        f4v st[4];
#pragma unroll
        for (int tj = 0; tj < 4; ++tj) st[tj] = (f4v){0.f, 0.f, 0.f, 0.f};
#pragma unroll
        for (int ks = 0; ks < 2; ++ks)
#pragma unroll
            for (int tj = 0; tj < 4; ++tj) {
                int kvl = tj * 16 + c;
                s8v kf = *(const s8v*)&Ks[kvl * 64 + (((ks * 4 + g) ^ (kvl & 7)) * 8)];
                st[tj] = __builtin_amdgcn_mfma_f32_16x16x32_bf16(kf, qf[ks], st[tj], 0, 0, 0);
            }

        s4v pf[4];
#pragma unroll
        for (int tj = 0; tj < 4; ++tj) {
            float p0 = __builtin_amdgcn_exp2f(st[tj][0]);
            float p1 = __builtin_amdgcn_exp2f(st[tj][1]);
            float p2 = __builtin_amdgcn_exp2f(st[tj][2]);
            float p3 = __builtin_amdgcn_exp2f(st[tj][3]);
            union { unsigned u[2]; s4v v; } pu;
            pu.u[0] = pk2(p0, p1);
            pu.u[1] = pk2(p2, p3);
            pf[tj] = pu.v;
        }

#pragma unroll
        for (int tjC = 0; tjC < 4; ++tjC) {
            liacc = __builtin_amdgcn_mfma_f32_16x16x16bf16_1k(pf[tjC], vone, liacc, 0, 0, 0);
#pragma unroll
            for (int tjd = 0; tjd < 4; ++tjd) {
                int d = tjd * 16 + c;
                int sd = tjC * 2 + (g >> 1);
                s4v vf = *(const s4v*)&Vt[d * 64 + ((sd ^ (d & 7)) * 8) + (g & 1) * 4];
                O[tjd] = __builtin_amdgcn_mfma_f32_16x16x16bf16_1k(pf[tjC], vf, O[tjd], 0, 0, 0);
            }
        }
        __syncthreads();
    }
#pragma unroll
    for (int i = 0; i < 4; ++i) {
        float linv = 1.0f / liacc[i];
        size_t rbase = ((size_t)(e * 1024) + q0 + g * 4 + i) * 1024 + h * 64;
#pragma unroll
        for (int tjd = 0; tjd < 4; ++tjd)
            ctx[rbase + tjd * 16 + c] = f2bf(O[tjd][i] * linv);
    }
}

// ---------------- xnb = bf16(rmsnorm(hb[b] + aob)) ----------------
__global__ void add_rmsnorm(const u16* __restrict__ hb, const u16* __restrict__ aob,
                            u16* __restrict__ xnb) {
    int row = blockIdx.x;          // e*SEQ + s
    int e = row >> 10;
    int b = e >> 1;
    int s = row & 1023;
    const u16* xr = hb + (((size_t)b * SEQ_ + s) << 10);
    const u16* ar = aob + ((size_t)row << 10);
    u16* o = xnb + ((size_t)row << 10);
    int t = threadIdx.x;
    u16x4 xv = *(const u16x4*)&xr[t * 4];
    u16x4 av = *(const u16x4*)&ar[t * 4];
    float v[4];
    float ss = 0.f;
#pragma unroll
    for (int i = 0; i < 4; ++i) {
        v[i] = bf2f(xv[i]) + bf2f(av[i]);
        ss += v[i] * v[i];
    }
    for (int off = 32; off >= 1; off >>= 1) ss += __shfl_down(ss, off, 64);
    __shared__ float wred[4];
    if ((t & 63) == 0) wred[t >> 6] = ss;
    __syncthreads();
    float tot = wred[0] + wred[1] + wred[2] + wred[3];
    float scale = rsqrtf(tot * (1.0f / 1024.0f) + EPS_);
    u16x4 ov;
#pragma unroll
    for (int i = 0; i < 4; ++i) ov[i] = f2bf(v[i] * scale);
    *(u16x4*)&o[t * 4] = ov;
}

// ---------------- out[b] = sum_j w_e * rmsnorm(xn[e] + mlp[e]) ----------------
__global__ void final_kernel(const u16* __restrict__ xnb, const u16* __restrict__ mlpb,
                             const float* __restrict__ flat_w, float* __restrict__ out) {
    int row = blockIdx.x;           // b*SEQ + s
    int b = row >> 10;
    int s = row & 1023;
    int t = threadIdx.x;
    __shared__ float wred[4];
    float res[4] = {0.f, 0.f, 0.f, 0.f};
    for (int j = 0; j < 2; ++j) {
        int e = 2 * b + j;
        size_t off = (((size_t)e * SEQ_ + s) << 10);
        u16x4 xv = *(const u16x4*)&xnb[off + t * 4];
        u16x4 mv = *(const u16x4*)&mlpb[off + t * 4];
        float v[4];
        float ss = 0.f;
#pragma unroll
        for (int i = 0; i < 4; ++i) {
            v[i] = bf2f(xv[i]) + bf2f(mv[i]);
            ss += v[i] * v[i];
        }
        for (int off2 = 32; off2 >= 1; off2 >>= 1) ss += __shfl_down(ss, off2, 64);
        if ((t & 63) == 0) wred[t >> 6] = ss;
        __syncthreads();
        float tot = wred[0] + wred[1] + wred[2] + wred[3];
        float scale = rsqrtf(tot * (1.0f / 1024.0f) + EPS_);
        float wgt = flat_w[e];
#pragma unroll
        for (int i = 0; i < 4; ++i) res[i] += wgt * v[i] * scale;
        __syncthreads();
    }
    float* o = out + ((size_t)row << 10);
    *(float4*)&o[t * 4] = make_float4(res[0], res[1], res[2], res[3]);
}

extern "C" void kernel_launch(void* const* d_in, const int* in_sizes, int n_in,
                              void* d_out, int out_size, void* d_ws, size_t ws_size,
                              hipStream_t stream) {
    const float* hidden = (const float*)d_in[0];
    const float* cosb   = (const float*)d_in[1];
    const float* sinb   = (const float*)d_in[2];
    const float* Wr     = (const float*)d_in[3];
    const float* temp   = (const float*)d_in[4];
    const float* Wqkv   = (const float*)d_in[5];
    const float* Wo     = (const float*)d_in[6];
    const float* Wgu    = (const float*)d_in[7];
    const float* Wd     = (const float*)d_in[8];
    float* out = (float*)d_out;
    float* out_logits = out + (size_t)B_ * SEQ_ * D_;

    char* base = (char*)d_ws;
    int*   flat_idx = (int*)base;
    float* flat_w   = (float*)(base + 128);
    float* routeP   = (float*)(base + 4096);          // 512 KB
    size_t off = (size_t)1 << 20;
    u16* WqkvT = (u16*)(base + off); off += (size_t)8 * 3072 * 1024 * 2;
    u16* WoT   = (u16*)(base + off); off += (size_t)8 * 1024 * 1024 * 2;
    u16* WguT  = (u16*)(base + off); off += (size_t)8 * 1536 * 1024 * 2;
    u16* WdT   = (u16*)(base + off); off += (size_t)8 * 1024 * 768 * 2;
    u16* hb    = (u16*)(base + off); off += (size_t)4 * 1024 * 1024 * 2;
    u16* Qb    = (u16*)(base + off); off += (size_t)8 * 1024 * 1024 * 2;
    u16* Kb    = (u16*)(base + off); off += (size_t)8 * 1024 * 1024 * 2;
    u16* Vb    = (u16*)(base + off); off += (size_t)8 * 1024 * 1024 * 2;
    u16* Vtg   = (u16*)(base + off); off += (size_t)8 * 1024 * 1024 * 2;
    u16* ctxb  = (u16*)(base + off); off += (size_t)8 * 1024 * 1024 * 2;
    u16* aob   = (u16*)(base + off); off += (size_t)8 * 1024 * 1024 * 2;
    u16* xnb   = (u16*)(base + off); off += (size_t)8 * 1024 * 1024 * 2;
    u16* actb  = (u16*)(base + off); off += (size_t)8 * 1024 * 768 * 2;
    u16* mlpb  = (u16*)(base + off); off += (size_t)8 * 1024 * 1024 * 2;

    route1<<<dim3(4, 32), 256, 0, stream>>>(hidden, routeP, hb);
    route2<<<4, 256, 0, stream>>>(routeP, Wr, temp, out_logits, flat_idx, flat_w);
    wtrans_all<<<12800, 256, 0, stream>>>(Wqkv, Wo, Wgu, Wd, WqkvT, WoT, WguT, WdT, flat_idx);

    gemm_qkv<<<dim3(12, 4, 8), 512, 0, stream>>>(hb, WqkvT, flat_idx, cosb, sinb, Qb, Kb, Vb);
    vtrans<<<dim3(16, 128), 256, 0, stream>>>(Vb, Vtg);
    attn_mfma<<<dim3(8, 16, 16), 256, 0, stream>>>(Qb, Kb, Vtg, ctxb);
    gemm_bf16<<<dim3(4, 4, 8), 512, 0, stream>>>(ctxb, WoT, aob, flat_idx, 1024, 1024, 1024, 1);
    add_rmsnorm<<<NE_ * SEQ_, 256, 0, stream>>>(hb, aob, xnb);
    gemm_wgu_silu<<<dim3(6, 4, 8), 512, 0, stream>>>(xnb, WguT, actb, flat_idx);
    gemm_bf16<<<dim3(4, 4, 8), 512, 0, stream>>>(actb, WdT, mlpb, flat_idx, 1024, 1024, 768, 1);
    final_kernel<<<B_ * SEQ_, 256, 0, stream>>>(xnb, mlpb, flat_w, out);
}

// Round 2
// 523.240 us; speedup vs baseline: 1.0421x; 1.0051x over previous
//
#include <hip/hip_runtime.h>
#include <hip/hip_bf16.h>
#include <math.h>

#define B_     4
#define SEQ_   1024
#define D_     1024
#define H_     16
#define NE_    8
#define INTER_ 768
#define EPS_   1e-5f

typedef unsigned short u16;
typedef __attribute__((ext_vector_type(8))) short s8v;      // 8 bf16 - MFMA A/B frag (K=32)
typedef __attribute__((ext_vector_type(4))) short s4v;      // 4 bf16 - MFMA A/B frag (K=16)
typedef __attribute__((ext_vector_type(4))) float f4v;      // MFMA C/D frag
typedef __attribute__((ext_vector_type(4))) unsigned short u16x4;
typedef __attribute__((ext_vector_type(8))) unsigned short u16x8;

__device__ __forceinline__ u16 f2bf(float x) {
    union { float f; unsigned u; } c; c.f = x;
    unsigned r = (c.u + 0x7FFFu + ((c.u >> 16) & 1u)) >> 16;
    return (u16)r;
}
__device__ __forceinline__ float bf2f(u16 h) {
    union { unsigned u; float f; } c; c.u = ((unsigned)h) << 16;
    return c.f;
}
__device__ __forceinline__ unsigned pk2(float a, float b) {
    union { float f; unsigned u; } x, y; x.f = a; y.f = b;
    return ((x.u + 0x8000u) >> 16) | ((y.u + 0x8000u) & 0xffff0000u);
}

#define GLDS16(gp, lp) \
    __builtin_amdgcn_global_load_lds((const __attribute__((address_space(1))) unsigned int*)(gp), \
                                     (__attribute__((address_space(3))) unsigned int*)(lp), 16, 0, 0)

#define BARRIER()  asm volatile("s_barrier" ::: "memory")

// ---------------- routing stage 1 + bf16 cast of hidden ----------------
__global__ void route1(const float* __restrict__ hidden, float* __restrict__ part,
                       u16* __restrict__ hb) {
    int b = blockIdx.x, ch = blockIdx.y, t = threadIdx.x;
    const float* xb = hidden + (size_t)b * SEQ_ * D_ + (size_t)ch * 32 * D_;
    u16* ho = hb + (size_t)b * SEQ_ * D_ + (size_t)ch * 32 * D_;
    float4 acc = make_float4(0.f, 0.f, 0.f, 0.f);
    for (int r = 0; r < 32; ++r) {
        float4 v = *(const float4*)&xb[(size_t)r * D_ + t * 4];
        acc.x += v.x; acc.y += v.y; acc.z += v.z; acc.w += v.w;
        u16x4 o = {f2bf(v.x), f2bf(v.y), f2bf(v.z), f2bf(v.w)};
        *(u16x4*)&ho[(size_t)r * D_ + t * 4] = o;
    }
    *(float4*)&part[((size_t)(b * 32 + ch)) * D_ + t * 4] = acc;
}

__global__ void route2(const float* __restrict__ part, const float* __restrict__ Wr,
                       const float* __restrict__ temp, float* __restrict__ out_logits,
                       int* __restrict__ flat_idx, float* __restrict__ flat_w) {
    __shared__ float col[1024];
    __shared__ float sm[8];
    int b = blockIdx.x, t = threadIdx.x;
    float4 s = make_float4(0.f, 0.f, 0.f, 0.f);
    for (int ch = 0; ch < 32; ++ch) {
        float4 v = *(const float4*)&part[((size_t)(b * 32 + ch)) * D_ + t * 4];
        s.x += v.x; s.y += v.y; s.z += v.z; s.w += v.w;
    }
    col[t * 4 + 0] = s.x * (1.f / 1024.f);
    col[t * 4 + 1] = s.y * (1.f / 1024.f);
    col[t * 4 + 2] = s.z * (1.f / 1024.f);
    col[t * 4 + 3] = s.w * (1.f / 1024.f);
    __syncthreads();
    int j = t >> 5, d0 = t & 31;
    float p = 0.f;
    for (int d = d0; d < 1024; d += 32) p += col[d] * Wr[j * 1024 + d];
    for (int off = 16; off >= 1; off >>= 1) p += __shfl_down(p, off, 32);
    if (d0 == 0) sm[j] = p;
    __syncthreads();
    if (t == 0) {
        float tc = temp[0];
        tc = fminf(fmaxf(tc, 0.1f), 10.0f);
        float lg[8];
        for (int jj = 0; jj < 8; ++jj) {
            lg[jj] = sm[jj] / tc;
            out_logits[b * 8 + jj] = lg[jj];
        }
        int i0 = 0; float v0 = lg[0];
        for (int jj = 1; jj < 8; ++jj) if (lg[jj] > v0) { v0 = lg[jj]; i0 = jj; }
        int i1 = -1; float v1 = -1e30f;
        for (int jj = 0; jj < 8; ++jj) if (jj != i0 && lg[jj] > v1) { v1 = lg[jj]; i1 = jj; }
        float e1 = expf(v1 - v0);
        flat_idx[2 * b]     = i0;
        flat_idx[2 * b + 1] = i1;
        flat_w[2 * b]       = 1.0f / (1.0f + e1);
        flat_w[2 * b + 1]   = e1 / (1.0f + e1);
    }
}

// ---------------- combined weight transpose+cast (all 4 weights, one dispatch) ----------------
// Blocks whose expert is not selected by routing exit early (weights never read).
__global__ __launch_bounds__(256) void wtrans_all(const float* __restrict__ Wqkv,
                                                  const float* __restrict__ Wo,
                                                  const float* __restrict__ Wgu,
                                                  const float* __restrict__ Wd,
                                                  u16* __restrict__ WqkvT, u16* __restrict__ WoT,
                                                  u16* __restrict__ WguT, u16* __restrict__ WdT,
                                                  const int* __restrict__ flat_idx) {
    int bid = blockIdx.x;
    const float* W; u16* Wt; int K, N, nx, gu = 0;
    if (bid < 6144)      { W = Wqkv; Wt = WqkvT; K = 1024; N = 3072; nx = 48; }
    else if (bid < 8192) { bid -= 6144;  W = Wo;  Wt = WoT;  K = 1024; N = 1024; nx = 16; }
    else if (bid < 11264){ bid -= 8192;  W = Wgu; Wt = WguT; K = 1024; N = 1536; nx = 24; gu = 1; }
    else                 { bid -= 11264; W = Wd;  Wt = WdT;  K = 768;  N = 1024; nx = 16; }
    int x = bid % nx; bid /= nx;
    int ny = K >> 6;
    int y = bid % ny;
    int e = bid / ny;

    bool used = false;
#pragma unroll
    for (int jj = 0; jj < 8; ++jj) used |= (flat_idx[jj] == e);
    if (!used) return;                       // block-uniform: e is uniform

    __shared__ float tile[64][65];
    int k0 = y * 64, n0 = x * 64;
    const float* Wp = W + (size_t)e * K * N;
    u16* Wtp = Wt + (size_t)e * K * N;
    int t = threadIdx.x;
    int kk = t >> 4, ns = t & 15;
#pragma unroll
    for (int p = 0; p < 4; ++p) {
        float4 v = *(const float4*)&Wp[(size_t)(k0 + kk + p * 16) * N + n0 + ns * 4];
        tile[kk + p * 16][ns * 4 + 0] = v.x;
        tile[kk + p * 16][ns * 4 + 1] = v.y;
        tile[kk + p * 16][ns * 4 + 2] = v.z;
        tile[kk + p * 16][ns * 4 + 3] = v.w;
    }
    __syncthreads();
    int nn = t >> 3, ks = t & 7;
#pragma unroll
    for (int p = 0; p < 2; ++p) {
        int n = n0 + nn + p * 32;
        int nd = n;
        if (gu) nd = (n < 768) ? ((n >> 4) << 5) + (n & 15)
                               : (((n - 768) >> 4) << 5) + 16 + (n & 15);
        u16x8 o;
#pragma unroll
        for (int jj = 0; jj < 8; ++jj) o[jj] = f2bf(tile[ks * 8 + jj][nn + p * 32]);
        *(u16x8*)&Wtp[(size_t)nd * K + k0 + ks * 8] = o;
    }
}

// ============ 128x128 / 4-wave / BK=32 GEMM core, 3-buffer counted-vmcnt pipeline ============
// LDS seg swizzle (per 128x32 buffer): stored seg ss of row r holds data seg ss^((r>>1)&3).
// Pipeline: stage tiles 0,1,2; per iter {compute(b[kt%3]); barrier; stage(kt+3 -> freed buf);
// vmcnt(8) [waits loads issued TWO tiles ago - never the fresh ones]; barrier}.
// 4 loads/thread/tile (A,B,A,B) -> vmcnt in units of 4. Tail: vmcnt 8 -> 4 -> 0.
#define GEMM_STAGE(Ap_, Wp_, Kp_, k0v, bo)                                                  \
    {                                                                                       \
        _Pragma("unroll") for (int it = 0; it < 2; ++it) {                                  \
            int p = it * 256 + w * 64 + lane;                                               \
            int row = p >> 2, seg = (p & 3) ^ ((row >> 1) & 3);                             \
            GLDS16((Ap_) + (size_t)(m0 + row) * (Kp_) + (k0v) + seg * 8,                    \
                   As + (bo) + (size_t)(it * 256 + w * 64) * 8);                            \
            GLDS16((Wp_) + (size_t)(n0 + row) * (Kp_) + (k0v) + seg * 8,                    \
                   Bs + (bo) + (size_t)(it * 256 + w * 64) * 8);                            \
        }                                                                                   \
    }

#define GEMM_CORE(Ap_, Wp_, Kp_)                                                            \
    f4v acc[4][4];                                                                          \
    _Pragma("unroll") for (int i = 0; i < 4; ++i)                                           \
        _Pragma("unroll") for (int jj = 0; jj < 4; ++jj) acc[i][jj] = (f4v){0.f,0.f,0.f,0.f}; \
    const int NT = (Kp_) / 32;                                                              \
    GEMM_STAGE(Ap_, Wp_, Kp_, 0, 0)                                                         \
    GEMM_STAGE(Ap_, Wp_, Kp_, 32, 4096)                                                     \
    GEMM_STAGE(Ap_, Wp_, Kp_, 64, 8192)                                                     \
    asm volatile("s_waitcnt vmcnt(8)" ::: "memory");                                        \
    BARRIER();                                                                              \
    int cb = 0;                                                                             \
    for (int kt = 0; kt < NT; ++kt) {                                                       \
        int bo = cb * 4096;                                                                 \
        s8v af[4], bfr[4];                                                                  \
        _Pragma("unroll") for (int ti = 0; ti < 4; ++ti) {                                  \
            int r = wm + ti * 16 + c;                                                       \
            af[ti]  = *(const s8v*)&As[bo + r * 32 + (g ^ ((r >> 1) & 3)) * 8];             \
        }                                                                                   \
        _Pragma("unroll") for (int tj = 0; tj < 4; ++tj) {                                  \
            int r = wn + tj * 16 + c;                                                       \
            bfr[tj] = *(const s8v*)&Bs[bo + r * 32 + (g ^ ((r >> 1) & 3)) * 8];             \
        }                                                                                   \
        __builtin_amdgcn_s_setprio(1);                                                      \
        _Pragma("unroll") for (int ti = 0; ti < 4; ++ti)                                    \
            _Pragma("unroll") for (int tj = 0; tj < 4; ++tj)                                \
                acc[ti][tj] = __builtin_amdgcn_mfma_f32_16x16x32_bf16(af[ti], bfr[tj], acc[ti][tj], 0, 0, 0); \
        __builtin_amdgcn_s_setprio(0);                                                      \
        BARRIER();                                                                          \
        if (kt + 3 < NT) {                                                                  \
            GEMM_STAGE(Ap_, Wp_, Kp_, (kt + 3) * 32, bo)                                    \
            asm volatile("s_waitcnt vmcnt(8)" ::: "memory");                                \
        } else if (kt + 2 < NT) {                                                           \
            asm volatile("s_waitcnt vmcnt(4)" ::: "memory");                                \
        } else {                                                                            \
            asm volatile("s_waitcnt vmcnt(0)" ::: "memory");                                \
        }                                                                                   \
        BARRIER();                                                                          \
        cb = (cb == 2) ? 0 : cb + 1;                                                        \
    }

// ---------------- generic bf16 MFMA GEMM (bf16 C) ----------------
__global__ __launch_bounds__(256) void gemm_bf16(const u16* __restrict__ Abase,
                                                 const u16* __restrict__ Wtbase,
                                                 u16* __restrict__ Cb,
                                                 const int* __restrict__ flat_idx,
                                                 int M, int N, int K, int aDiv) {
    __shared__ __align__(16) u16 As[3 * 128 * 32];
    __shared__ __align__(16) u16 Bs[3 * 128 * 32];
    int e = blockIdx.z;
    const u16* A  = Abase + (size_t)(e / aDiv) * M * K;
    const u16* Wt = Wtbase + (size_t)flat_idx[e] * N * K;
    int m0 = blockIdx.y * 128, n0 = blockIdx.x * 128;
    int t = threadIdx.x, lane = t & 63, w = t >> 6;
    int g = lane >> 4, c = lane & 15;
    int wm = (w >> 1) * 64, wn = (w & 1) * 64;

    GEMM_CORE(A, Wt, K)

    u16* C = Cb + (size_t)e * M * N;
#pragma unroll
    for (int ti = 0; ti < 4; ++ti)
#pragma unroll
        for (int tj = 0; tj < 4; ++tj)
#pragma unroll
            for (int i = 0; i < 4; ++i)
                C[(size_t)(m0 + wm + ti * 16 + g * 4 + i) * N + n0 + wn + tj * 16 + c] = f2bf(acc[ti][tj][i]);
}

// ---------------- qkv GEMM with fused RoPE/scale/split epilogue ----------------
__global__ __launch_bounds__(256) void gemm_qkv(const u16* __restrict__ Abase,
                                                const u16* __restrict__ Wtbase,
                                                const int* __restrict__ flat_idx,
                                                const float* __restrict__ cosb,
                                                const float* __restrict__ sinb,
                                                u16* __restrict__ Qb, u16* __restrict__ Kb,
                                                u16* __restrict__ Vb) {
    __shared__ __align__(16) u16 As[3 * 128 * 32];
    __shared__ __align__(16) u16 Bs[3 * 128 * 32];
    const int K = 1024, N = 3072;
    int e = blockIdx.z;
    const u16* A  = Abase + (size_t)(e >> 1) * 1024 * K;
    const u16* Wt = Wtbase + (size_t)flat_idx[e] * N * K;
    int m0 = blockIdx.y * 128, n0 = blockIdx.x * 128;
    int t = threadIdx.x, lane = t & 63, w = t >> 6;
    int g = lane >> 4, c = lane & 15;
    int wm = (w >> 1) * 64, wn = (w & 1) * 64;

    GEMM_CORE(A, Wt, K)

    int col0 = n0 + wn;                 // multiple of 64
    int sb = m0 + wm + g * 4;
    if (col0 < 2048) {
        bool isq = col0 < 1024;
        u16* dst = isq ? Qb : Kb;
        int h = (col0 & 1023) >> 6;
        const float scl = isq ? 0.125f * 1.44269504f : 1.0f;
#pragma unroll
        for (int ti = 0; ti < 4; ++ti)
#pragma unroll
            for (int i = 0; i < 4; ++i) {
                int s = sb + ti * 16 + i;
                size_t ob = ((size_t)(e * 1024) + s) * 1024 + h * 64;
#pragma unroll
                for (int tj = 0; tj < 2; ++tj) {
                    int d = tj * 16 + c;
                    float x1 = acc[ti][tj][i], x2 = acc[ti][tj + 2][i];
                    float c1 = cosb[s * 64 + d],      s1 = sinb[s * 64 + d];
                    float c2 = cosb[s * 64 + d + 32], s2 = sinb[s * 64 + d + 32];
                    dst[ob + d]      = f2bf((x1 * c1 - x2 * s1) * scl);
                    dst[ob + d + 32] = f2bf((x2 * c2 + x1 * s2) * scl);
                }
            }
    } else {
        int vcol = col0 - 2048;
#pragma unroll
        for (int ti = 0; ti < 4; ++ti)
#pragma unroll
            for (int tj = 0; tj < 4; ++tj)
#pragma unroll
                for (int i = 0; i < 4; ++i)
                    Vb[((size_t)(e * 1024) + sb + ti * 16 + i) * 1024 + vcol + tj * 16 + c] = f2bf(acc[ti][tj][i]);
    }
}

// ---------------- Wgu GEMM (interleaved columns) + fused SiLU*up epilogue ----------------
__global__ __launch_bounds__(256) void gemm_wgu_silu(const u16* __restrict__ Abase,
                                                     const u16* __restrict__ Wtbase,
                                                     u16* __restrict__ act,
                                                     const int* __restrict__ flat_idx) {
    __shared__ __align__(16) u16 As[3 * 128 * 32];
    __shared__ __align__(16) u16 Bs[3 * 128 * 32];
    const int K = 1024, N = 1536;
    int e = blockIdx.z;
    const u16* A  = Abase + (size_t)e * 1024 * K;
    const u16* Wt = Wtbase + (size_t)flat_idx[e] * N * K;
    int m0 = blockIdx.y * 128, n0 = blockIdx.x * 128;
    int t = threadIdx.x, lane = t & 63, w = t >> 6;
    int g = lane >> 4, c = lane & 15;
    int wm = (w >> 1) * 64, wn = (w & 1) * 64;

    GEMM_CORE(A, Wt, K)

    int col0 = n0 + wn;
    int oc0 = (col0 >> 1) + c;          // act col for tj pair (0,1); +16 for (2,3)
    int sb = m0 + wm + g * 4;
#pragma unroll
    for (int ti = 0; ti < 4; ++ti)
#pragma unroll
        for (int i = 0; i < 4; ++i) {
            size_t rb = ((size_t)(e * 1024) + sb + ti * 16 + i) * 768;
#pragma unroll
            for (int pr = 0; pr < 2; ++pr) {
                float gt = acc[ti][pr * 2][i];
                float up = acc[ti][pr * 2 + 1][i];
                act[rb + oc0 + pr * 16] = f2bf(gt / (1.f + __expf(-gt)) * up);
            }
        }
}

// ---------------- V transpose: Vb[e][s][d] -> Vtg[e][h][d=64][kv=1024] ----------------
__global__ __launch_bounds__(256) void vtrans(const u16* __restrict__ Vb, u16* __restrict__ Vtg) {
    __shared__ __align__(16) u16 tile[64 * 72];
    int s0 = blockIdx.x * 64;
    int eh = blockIdx.y;
    int e = eh >> 4, h = eh & 15;
    int t = threadIdx.x;
#pragma unroll
    for (int it = 0; it < 2; ++it) {
        int p = it * 256 + t;
        int sr = p >> 3, ds = p & 7;
        u16x8 v = *(const u16x8*)&Vb[((size_t)(e * 1024) + s0 + sr) * 1024 + h * 64 + ds * 8];
        *(u16x8*)&tile[sr * 72 + ds * 8] = v;
    }
    __syncthreads();
#pragma unroll
    for (int it = 0; it < 2; ++it) {
        int p = it * 256 + t;
        int d = p >> 3, ks = p & 7;
        u16x8 o;
#pragma unroll
        for (int jj = 0; jj < 8; ++jj) o[jj] = tile[(ks * 8 + jj) * 72 + d];
        *(u16x8*)&Vtg[((size_t)((e * 16 + h) * 64) + d) * 1024 + s0 + ks * 8] = o;
    }
}

// ---------------- MFMA flash attention (S^T = K Q^T; register P) ----------------
// Same counted-vmcnt pipeline: 2 buffers, 4 loads/thread/tile, vmcnt(4) waits loads
// issued one full kv-tile earlier; multi-block TLP hides the rest.
#define ATTN_STAGE(ktv, bo)                                                                 \
    {                                                                                       \
        _Pragma("unroll") for (int it = 0; it < 2; ++it) {                                  \
            int p = it * 256 + w * 64 + lane;                                               \
            int row = p >> 3, ss = p & 7;                                                   \
            GLDS16(Kb + ((size_t)(e * 1024 + (ktv) * 64 + row)) * 1024 + h * 64 + (ss ^ (row & 7)) * 8, \
                   Ks + (bo) + (size_t)(it * 256 + w * 64) * 8);                            \
            GLDS16(Vtg + ((size_t)((e * 16 + h) * 64 + row)) * 1024 + (ktv) * 64 + (ss ^ (row & 7)) * 8, \
                   Vt + (bo) + (size_t)(it * 256 + w * 64) * 8);                            \
        }                                                                                   \
    }

__global__ __launch_bounds__(256) void attn_mfma(const u16* __restrict__ Qb, const u16* __restrict__ Kb,
                                                 const u16* __restrict__ Vtg, u16* __restrict__ ctx) {
    __shared__ __align__(16) u16 Ks[2 * 64 * 64];
    __shared__ __align__(16) u16 Vt[2 * 64 * 64];
    int e = blockIdx.x, h = blockIdx.y, qt = blockIdx.z;
    int t = threadIdx.x, lane = t & 63, w = t >> 6;
    int g = lane >> 4, c = lane & 15;
    int q0 = qt * 64 + w * 16;

    s8v qf[2];
#pragma unroll
    for (int ks = 0; ks < 2; ++ks)
        qf[ks] = *(const s8v*)&Qb[((size_t)(e * 1024) + q0 + c) * 1024 + h * 64 + ks * 32 + g * 8];

    f4v O[4];
#pragma unroll
    for (int tj = 0; tj < 4; ++tj) O[tj] = (f4v){0.f, 0.f, 0.f, 0.f};
    f4v liacc = (f4v){0.f, 0.f, 0.f, 0.f};
    const s4v vone = {(short)0x3F80, (short)0x3F80, (short)0x3F80, (short)0x3F80};

    ATTN_STAGE(0, 0)
    ATTN_STAGE(1, 4096)
    asm volatile("s_waitcnt vmcnt(4)" ::: "memory");
    BARRIER();
    int cb = 0;

    for (int kt = 0; kt < 16; ++kt) {
        int bo = cb * 4096;
        f4v st[4];
#pragma unroll
        for (int tj = 0; tj < 4; ++tj) st[tj] = (f4v){0.f, 0.f, 0.f, 0.f};
#pragma unroll
        for (int ks = 0; ks < 2; ++ks)
#pragma unroll
            for (int tj = 0; tj < 4; ++tj) {
                int kvl = tj * 16 + c;
                s8v kf = *(const s8v*)&Ks[bo + kvl * 64 + (((ks * 4 + g) ^ (kvl & 7)) * 8)];
                st[tj] = __builtin_amdgcn_mfma_f32_16x16x32_bf16(kf, qf[ks], st[tj], 0, 0, 0);
            }

        s4v pf[4];
#pragma unroll
        for (int tj = 0; tj < 4; ++tj) {
            float p0 = __builtin_amdgcn_exp2f(st[tj][0]);
            float p1 = __builtin_amdgcn_exp2f(st[tj][1]);
            float p2 = __builtin_amdgcn_exp2f(st[tj][2]);
            float p3 = __builtin_amdgcn_exp2f(st[tj][3]);
            union { unsigned u[2]; s4v v; } pu;
            pu.u[0] = pk2(p0, p1);
            pu.u[1] = pk2(p2, p3);
            pf[tj] = pu.v;
        }

#pragma unroll
        for (int tjC = 0; tjC < 4; ++tjC) {
            liacc = __builtin_amdgcn_mfma_f32_16x16x16bf16_1k(pf[tjC], vone, liacc, 0, 0, 0);
#pragma unroll
            for (int tjd = 0; tjd < 4; ++tjd) {
                int d = tjd * 16 + c;
                int sd = tjC * 2 + (g >> 1);
                s4v vf = *(const s4v*)&Vt[bo + d * 64 + ((sd ^ (d & 7)) * 8) + (g & 1) * 4];
                O[tjd] = __builtin_amdgcn_mfma_f32_16x16x16bf16_1k(pf[tjC], vf, O[tjd], 0, 0, 0);
            }
        }

        BARRIER();
        if (kt + 2 < 16) {
            ATTN_STAGE(kt + 2, bo)
            asm volatile("s_waitcnt vmcnt(4)" ::: "memory");
        } else {
            asm volatile("s_waitcnt vmcnt(0)" ::: "memory");
        }
        BARRIER();
        cb ^= 1;
    }
#pragma unroll
    for (int i = 0; i < 4; ++i) {
        float linv = 1.0f / liacc[i];
        size_t rbase = ((size_t)(e * 1024) + q0 + g * 4 + i) * 1024 + h * 64;
#pragma unroll
        for (int tjd = 0; tjd < 4; ++tjd)
            ctx[rbase + tjd * 16 + c] = f2bf(O[tjd][i] * linv);
    }
}

// ---------------- xnb = bf16(rmsnorm(hb[b] + aob)) ----------------
__global__ void add_rmsnorm(const u16* __restrict__ hb, const u16* __restrict__ aob,
                            u16* __restrict__ xnb) {
    int row = blockIdx.x;          // e*SEQ + s
    int e = row >> 10;
    int b = e >> 1;
    int s = row & 1023;
    const u16* xr = hb + (((size_t)b * SEQ_ + s) << 10);
    const u16* ar = aob + ((size_t)row << 10);
    u16* o = xnb + ((size_t)row << 10);
    int t = threadIdx.x;
    u16x4 xv = *(const u16x4*)&xr[t * 4];
    u16x4 av = *(const u16x4*)&ar[t * 4];
    float v[4];
    float ss = 0.f;
#pragma unroll
    for (int i = 0; i < 4; ++i) {
        v[i] = bf2f(xv[i]) + bf2f(av[i]);
        ss += v[i] * v[i];
    }
    for (int off = 32; off >= 1; off >>= 1) ss += __shfl_down(ss, off, 64);
    __shared__ float wred[4];
    if ((t & 63) == 0) wred[t >> 6] = ss;
    __syncthreads();
    float tot = wred[0] + wred[1] + wred[2] + wred[3];
    float scale = rsqrtf(tot * (1.0f / 1024.0f) + EPS_);
    u16x4 ov;
#pragma unroll
    for (int i = 0; i < 4; ++i) ov[i] = f2bf(v[i] * scale);
    *(u16x4*)&o[t * 4] = ov;
}

// ---------------- out[b] = sum_j w_e * rmsnorm(xn[e] + mlp[e]) ----------------
__global__ void final_kernel(const u16* __restrict__ xnb, const u16* __restrict__ mlpb,
                             const float* __restrict__ flat_w, float* __restrict__ out) {
    int row = blockIdx.x;           // b*SEQ + s
    int b = row >> 10;
    int s = row & 1023;
    int t = threadIdx.x;
    __shared__ float wred[4];
    float res[4] = {0.f, 0.f, 0.f, 0.f};
    for (int j = 0; j < 2; ++j) {
        int e = 2 * b + j;
        size_t off = (((size_t)e * SEQ_ + s) << 10);
        u16x4 xv = *(const u16x4*)&xnb[off + t * 4];
        u16x4 mv = *(const u16x4*)&mlpb[off + t * 4];
        float v[4];
        float ss = 0.f;
#pragma unroll
        for (int i = 0; i < 4; ++i) {
            v[i] = bf2f(xv[i]) + bf2f(mv[i]);
            ss += v[i] * v[i];
        }
        for (int off2 = 32; off2 >= 1; off2 >>= 1) ss += __shfl_down(ss, off2, 64);
        if ((t & 63) == 0) wred[t >> 6] = ss;
        __syncthreads();
        float tot = wred[0] + wred[1] + wred[2] + wred[3];
        float scale = rsqrtf(tot * (1.0f / 1024.0f) + EPS_);
        float wgt = flat_w[e];
#pragma unroll
        for (int i = 0; i < 4; ++i) res[i] += wgt * v[i] * scale;
        __syncthreads();
    }
    float* o = out + ((size_t)row << 10);
    *(float4*)&o[t * 4] = make_float4(res[0], res[1], res[2], res[3]);
}

extern "C" void kernel_launch(void* const* d_in, const int* in_sizes, int n_in,
                              void* d_out, int out_size, void* d_ws, size_t ws_size,
                              hipStream_t stream) {
    const float* hidden = (const float*)d_in[0];
    const float* cosb   = (const float*)d_in[1];
    const float* sinb   = (const float*)d_in[2];
    const float* Wr     = (const float*)d_in[3];
    const float* temp   = (const float*)d_in[4];
    const float* Wqkv   = (const float*)d_in[5];
    const float* Wo     = (const float*)d_in[6];
    const float* Wgu    = (const float*)d_in[7];
    const float* Wd     = (const float*)d_in[8];
    float* out = (float*)d_out;
    float* out_logits = out + (size_t)B_ * SEQ_ * D_;

    char* base = (char*)d_ws;
    int*   flat_idx = (int*)base;
    float* flat_w   = (float*)(base + 128);
    float* routeP   = (float*)(base + 4096);          // 512 KB
    size_t off = (size_t)1 << 20;
    u16* WqkvT = (u16*)(base + off); off += (size_t)8 * 3072 * 1024 * 2;
    u16* WoT   = (u16*)(base + off); off += (size_t)8 * 1024 * 1024 * 2;
    u16* WguT  = (u16*)(base + off); off += (size_t)8 * 1536 * 1024 * 2;
    u16* WdT   = (u16*)(base + off); off += (size_t)8 * 1024 * 768 * 2;
    u16* hb    = (u16*)(base + off); off += (size_t)4 * 1024 * 1024 * 2;
    u16* Qb    = (u16*)(base + off); off += (size_t)8 * 1024 * 1024 * 2;
    u16* Kb    = (u16*)(base + off); off += (size_t)8 * 1024 * 1024 * 2;
    u16* Vb    = (u16*)(base + off); off += (size_t)8 * 1024 * 1024 * 2;
    u16* Vtg   = (u16*)(base + off); off += (size_t)8 * 1024 * 1024 * 2;
    u16* ctxb  = (u16*)(base + off); off += (size_t)8 * 1024 * 1024 * 2;
    u16* aob   = (u16*)(base + off); off += (size_t)8 * 1024 * 1024 * 2;
    u16* xnb   = (u16*)(base + off); off += (size_t)8 * 1024 * 1024 * 2;
    u16* actb  = (u16*)(base + off); off += (size_t)8 * 1024 * 768 * 2;
    u16* mlpb  = (u16*)(base + off); off += (size_t)8 * 1024 * 1024 * 2;

    route1<<<dim3(4, 32), 256, 0, stream>>>(hidden, routeP, hb);
    route2<<<4, 256, 0, stream>>>(routeP, Wr, temp, out_logits, flat_idx, flat_w);
    wtrans_all<<<12800, 256, 0, stream>>>(Wqkv, Wo, Wgu, Wd, WqkvT, WoT, WguT, WdT, flat_idx);

    gemm_qkv<<<dim3(24, 8, 8), 256, 0, stream>>>(hb, WqkvT, flat_idx, cosb, sinb, Qb, Kb, Vb);
    vtrans<<<dim3(16, 128), 256, 0, stream>>>(Vb, Vtg);
    attn_mfma<<<dim3(8, 16, 16), 256, 0, stream>>>(Qb, Kb, Vtg, ctxb);
    gemm_bf16<<<dim3(8, 8, 8), 256, 0, stream>>>(ctxb, WoT, aob, flat_idx, 1024, 1024, 1024, 1);
    add_rmsnorm<<<NE_ * SEQ_, 256, 0, stream>>>(hb, aob, xnb);
    gemm_wgu_silu<<<dim3(12, 8, 8), 256, 0, stream>>>(xnb, WguT, actb, flat_idx);
    gemm_bf16<<<dim3(8, 8, 8), 256, 0, stream>>>(actb, WdT, mlpb, flat_idx, 1024, 1024, 768, 1);
    final_kernel<<<B_ * SEQ_, 256, 0, stream>>>(xnb, mlpb, flat_w, out);
}

// Round 3
// 484.899 us; speedup vs baseline: 1.1245x; 1.0791x over previous
//
#include <hip/hip_runtime.h>
#include <hip/hip_bf16.h>
#include <math.h>

#define B_     4
#define SEQ_   1024
#define D_     1024
#define H_     16
#define NE_    8
#define INTER_ 768
#define EPS_   1e-5f

typedef unsigned short u16;
typedef __attribute__((ext_vector_type(8))) short s8v;      // 8 bf16 - MFMA A/B frag (K=32)
typedef __attribute__((ext_vector_type(4))) short s4v;      // 4 bf16 - MFMA A/B frag (K=16)
typedef __attribute__((ext_vector_type(4))) float f4v;      // MFMA C/D frag
typedef __attribute__((ext_vector_type(4))) unsigned short u16x4;
typedef __attribute__((ext_vector_type(8))) unsigned short u16x8;

__device__ __forceinline__ u16 f2bf(float x) {
    union { float f; unsigned u; } c; c.f = x;
    unsigned r = (c.u + 0x7FFFu + ((c.u >> 16) & 1u)) >> 16;
    return (u16)r;
}
__device__ __forceinline__ float bf2f(u16 h) {
    union { unsigned u; float f; } c; c.u = ((unsigned)h) << 16;
    return c.f;
}
__device__ __forceinline__ unsigned pk2(float a, float b) {
    union { float f; unsigned u; } x, y; x.f = a; y.f = b;
    return ((x.u + 0x8000u) >> 16) | ((y.u + 0x8000u) & 0xffff0000u);
}

#define GLDS16(gp, lp) \
    __builtin_amdgcn_global_load_lds((const __attribute__((address_space(1))) unsigned int*)(gp), \
                                     (__attribute__((address_space(3))) unsigned int*)(lp), 16, 0, 0)

#define BARRIER()  asm volatile("s_barrier" ::: "memory")

// ---------------- routing stage 1 + bf16 cast of hidden ----------------
__global__ void route1(const float* __restrict__ hidden, float* __restrict__ part,
                       u16* __restrict__ hb) {
    int b = blockIdx.x, ch = blockIdx.y, t = threadIdx.x;
    const float* xb = hidden + (size_t)b * SEQ_ * D_ + (size_t)ch * 32 * D_;
    u16* ho = hb + (size_t)b * SEQ_ * D_ + (size_t)ch * 32 * D_;
    float4 acc = make_float4(0.f, 0.f, 0.f, 0.f);
    for (int r = 0; r < 32; ++r) {
        float4 v = *(const float4*)&xb[(size_t)r * D_ + t * 4];
        acc.x += v.x; acc.y += v.y; acc.z += v.z; acc.w += v.w;
        u16x4 o = {f2bf(v.x), f2bf(v.y), f2bf(v.z), f2bf(v.w)};
        *(u16x4*)&ho[(size_t)r * D_ + t * 4] = o;
    }
    *(float4*)&part[((size_t)(b * 32 + ch)) * D_ + t * 4] = acc;
}

__global__ void route2(const float* __restrict__ part, const float* __restrict__ Wr,
                       const float* __restrict__ temp, float* __restrict__ out_logits,
                       int* __restrict__ flat_idx, float* __restrict__ flat_w) {
    __shared__ float col[1024];
    __shared__ float sm[8];
    int b = blockIdx.x, t = threadIdx.x;
    float4 s = make_float4(0.f, 0.f, 0.f, 0.f);
    for (int ch = 0; ch < 32; ++ch) {
        float4 v = *(const float4*)&part[((size_t)(b * 32 + ch)) * D_ + t * 4];
        s.x += v.x; s.y += v.y; s.z += v.z; s.w += v.w;
    }
    col[t * 4 + 0] = s.x * (1.f / 1024.f);
    col[t * 4 + 1] = s.y * (1.f / 1024.f);
    col[t * 4 + 2] = s.z * (1.f / 1024.f);
    col[t * 4 + 3] = s.w * (1.f / 1024.f);
    __syncthreads();
    int j = t >> 5, d0 = t & 31;
    float p = 0.f;
    for (int d = d0; d < 1024; d += 32) p += col[d] * Wr[j * 1024 + d];
    for (int off = 16; off >= 1; off >>= 1) p += __shfl_down(p, off, 32);
    if (d0 == 0) sm[j] = p;
    __syncthreads();
    if (t == 0) {
        float tc = temp[0];
        tc = fminf(fmaxf(tc, 0.1f), 10.0f);
        float lg[8];
        for (int jj = 0; jj < 8; ++jj) {
            lg[jj] = sm[jj] / tc;
            out_logits[b * 8 + jj] = lg[jj];
        }
        int i0 = 0; float v0 = lg[0];
        for (int jj = 1; jj < 8; ++jj) if (lg[jj] > v0) { v0 = lg[jj]; i0 = jj; }
        int i1 = -1; float v1 = -1e30f;
        for (int jj = 0; jj < 8; ++jj) if (jj != i0 && lg[jj] > v1) { v1 = lg[jj]; i1 = jj; }
        float e1 = expf(v1 - v0);
        flat_idx[2 * b]     = i0;
        flat_idx[2 * b + 1] = i1;
        flat_w[2 * b]       = 1.0f / (1.0f + e1);
        flat_w[2 * b + 1]   = e1 / (1.0f + e1);
    }
}

// ---------------- combined weight transpose+cast (all 4 weights, one dispatch) ----------------
// Blocks whose expert is not selected by routing exit early (weights never read).
__global__ __launch_bounds__(256) void wtrans_all(const float* __restrict__ Wqkv,
                                                  const float* __restrict__ Wo,
                                                  const float* __restrict__ Wgu,
                                                  const float* __restrict__ Wd,
                                                  u16* __restrict__ WqkvT, u16* __restrict__ WoT,
                                                  u16* __restrict__ WguT, u16* __restrict__ WdT,
                                                  const int* __restrict__ flat_idx) {
    int bid = blockIdx.x;
    const float* W; u16* Wt; int K, N, nx, gu = 0;
    if (bid < 6144)      { W = Wqkv; Wt = WqkvT; K = 1024; N = 3072; nx = 48; }
    else if (bid < 8192) { bid -= 6144;  W = Wo;  Wt = WoT;  K = 1024; N = 1024; nx = 16; }
    else if (bid < 11264){ bid -= 8192;  W = Wgu; Wt = WguT; K = 1024; N = 1536; nx = 24; gu = 1; }
    else                 { bid -= 11264; W = Wd;  Wt = WdT;  K = 768;  N = 1024; nx = 16; }
    int x = bid % nx; bid /= nx;
    int ny = K >> 6;
    int y = bid % ny;
    int e = bid / ny;

    bool used = false;
#pragma unroll
    for (int jj = 0; jj < 8; ++jj) used |= (flat_idx[jj] == e);
    if (!used) return;                       // block-uniform: e is uniform

    __shared__ float tile[64][65];
    int k0 = y * 64, n0 = x * 64;
    const float* Wp = W + (size_t)e * K * N;
    u16* Wtp = Wt + (size_t)e * K * N;
    int t = threadIdx.x;
    int kk = t >> 4, ns = t & 15;
#pragma unroll
    for (int p = 0; p < 4; ++p) {
        float4 v = *(const float4*)&Wp[(size_t)(k0 + kk + p * 16) * N + n0 + ns * 4];
        tile[kk + p * 16][ns * 4 + 0] = v.x;
        tile[kk + p * 16][ns * 4 + 1] = v.y;
        tile[kk + p * 16][ns * 4 + 2] = v.z;
        tile[kk + p * 16][ns * 4 + 3] = v.w;
    }
    __syncthreads();
    int nn = t >> 3, ks = t & 7;
#pragma unroll
    for (int p = 0; p < 2; ++p) {
        int n = n0 + nn + p * 32;
        int nd = n;
        if (gu) nd = (n < 768) ? ((n >> 4) << 5) + (n & 15)
                               : (((n - 768) >> 4) << 5) + 16 + (n & 15);
        u16x8 o;
#pragma unroll
        for (int jj = 0; jj < 8; ++jj) o[jj] = f2bf(tile[ks * 8 + jj][nn + p * 32]);
        *(u16x8*)&Wtp[(size_t)nd * K + k0 + ks * 8] = o;
    }
}

// ============ 128x128 / 4-wave / BK=64 single-buffer GEMM core ============
// 2x the MFMA work per exposed load-latency window vs BK=32 (the r0-r2 invariant
// was ~2000cy latency per tile; amortize it over 32 MFMA instead of 16).
// LDS: As/Bs 128 rows x 8 segs of 8 bf16 (64 cols). Stored seg ss of row r holds
// data seg ss ^ (r & 7) (pre-swizzled global source, linear LDS dest - both-sides rule).
// Read: data seg (ks*4+g) at row r -> stored seg (ks*4+g)^(r&7); within a 16-lane
// phase this is 2-way bank aliasing = free (r0 measured 0 conflicts, same scheme).
#define GEMM_CORE64(Ap_, Wp_, Kp_)                                                          \
    f4v acc[4][4];                                                                          \
    _Pragma("unroll") for (int i_ = 0; i_ < 4; ++i_)                                        \
        _Pragma("unroll") for (int j_ = 0; j_ < 4; ++j_) acc[i_][j_] = (f4v){0.f,0.f,0.f,0.f}; \
    const u16* gA[4]; const u16* gB[4];                                                     \
    _Pragma("unroll") for (int it = 0; it < 4; ++it) {                                      \
        int p_ = it * 256 + t;                                                              \
        int row_ = p_ >> 3, seg_ = (p_ & 7) ^ (row_ & 7);                                   \
        gA[it] = (Ap_) + (size_t)(m0 + row_) * (Kp_) + seg_ * 8;                            \
        gB[it] = (Wp_) + (size_t)(n0 + row_) * (Kp_) + seg_ * 8;                            \
    }                                                                                       \
    const int NT = (Kp_) / 64;                                                              \
    for (int kt = 0; kt < NT; ++kt) {                                                       \
        _Pragma("unroll") for (int it = 0; it < 4; ++it) {                                  \
            GLDS16(gA[it] + (size_t)kt * 64, As + (size_t)(it * 256 + w * 64) * 8);         \
            GLDS16(gB[it] + (size_t)kt * 64, Bs + (size_t)(it * 256 + w * 64) * 8);         \
        }                                                                                   \
        __syncthreads();                                                                    \
        _Pragma("unroll") for (int ks = 0; ks < 2; ++ks) {                                  \
            s8v af[4], bfr[4];                                                              \
            _Pragma("unroll") for (int ti = 0; ti < 4; ++ti) {                              \
                int r = wm + ti * 16 + c;                                                   \
                af[ti]  = *(const s8v*)&As[r * 64 + (((ks * 4 + g) ^ (r & 7)) * 8)];        \
            }                                                                               \
            _Pragma("unroll") for (int tj = 0; tj < 4; ++tj) {                              \
                int r = wn + tj * 16 + c;                                                   \
                bfr[tj] = *(const s8v*)&Bs[r * 64 + (((ks * 4 + g) ^ (r & 7)) * 8)];        \
            }                                                                               \
            __builtin_amdgcn_s_setprio(1);                                                  \
            _Pragma("unroll") for (int ti = 0; ti < 4; ++ti)                                \
                _Pragma("unroll") for (int tj = 0; tj < 4; ++tj)                            \
                    acc[ti][tj] = __builtin_amdgcn_mfma_f32_16x16x32_bf16(af[ti], bfr[tj], acc[ti][tj], 0, 0, 0); \
            __builtin_amdgcn_s_setprio(0);                                                  \
        }                                                                                   \
        __syncthreads();                                                                    \
    }

// ---------------- generic bf16 MFMA GEMM (bf16 C) ----------------
__global__ __launch_bounds__(256) void gemm_bf16(const u16* __restrict__ Abase,
                                                 const u16* __restrict__ Wtbase,
                                                 u16* __restrict__ Cb,
                                                 const int* __restrict__ flat_idx,
                                                 int M, int N, int K, int aDiv) {
    __shared__ __align__(16) u16 As[128 * 64];
    __shared__ __align__(16) u16 Bs[128 * 64];
    int e = blockIdx.z;
    const u16* A  = Abase + (size_t)(e / aDiv) * M * K;
    const u16* Wt = Wtbase + (size_t)flat_idx[e] * N * K;
    int m0 = blockIdx.y * 128, n0 = blockIdx.x * 128;
    int t = threadIdx.x, lane = t & 63, w = t >> 6;
    int g = lane >> 4, c = lane & 15;
    int wm = (w >> 1) * 64, wn = (w & 1) * 64;

    GEMM_CORE64(A, Wt, K)

    u16* C = Cb + (size_t)e * M * N;
#pragma unroll
    for (int ti = 0; ti < 4; ++ti)
#pragma unroll
        for (int tj = 0; tj < 4; ++tj)
#pragma unroll
            for (int i = 0; i < 4; ++i)
                C[(size_t)(m0 + wm + ti * 16 + g * 4 + i) * N + n0 + wn + tj * 16 + c] = f2bf(acc[ti][tj][i]);
}

// ---------------- qkv GEMM with fused RoPE/scale/split epilogue ----------------
__global__ __launch_bounds__(256) void gemm_qkv(const u16* __restrict__ Abase,
                                                const u16* __restrict__ Wtbase,
                                                const int* __restrict__ flat_idx,
                                                const float* __restrict__ cosb,
                                                const float* __restrict__ sinb,
                                                u16* __restrict__ Qb, u16* __restrict__ Kb,
                                                u16* __restrict__ Vb) {
    __shared__ __align__(16) u16 As[128 * 64];
    __shared__ __align__(16) u16 Bs[128 * 64];
    const int K = 1024, N = 3072;
    int e = blockIdx.z;
    const u16* A  = Abase + (size_t)(e >> 1) * 1024 * K;
    const u16* Wt = Wtbase + (size_t)flat_idx[e] * N * K;
    int m0 = blockIdx.y * 128, n0 = blockIdx.x * 128;
    int t = threadIdx.x, lane = t & 63, w = t >> 6;
    int g = lane >> 4, c = lane & 15;
    int wm = (w >> 1) * 64, wn = (w & 1) * 64;

    GEMM_CORE64(A, Wt, K)

    int col0 = n0 + wn;                 // multiple of 64
    int sb = m0 + wm + g * 4;
    if (col0 < 2048) {
        bool isq = col0 < 1024;
        u16* dst = isq ? Qb : Kb;
        int h = (col0 & 1023) >> 6;
        const float scl = isq ? 0.125f * 1.44269504f : 1.0f;
#pragma unroll
        for (int ti = 0; ti < 4; ++ti)
#pragma unroll
            for (int i = 0; i < 4; ++i) {
                int s = sb + ti * 16 + i;
                size_t ob = ((size_t)(e * 1024) + s) * 1024 + h * 64;
#pragma unroll
                for (int tj = 0; tj < 2; ++tj) {
                    int d = tj * 16 + c;
                    float x1 = acc[ti][tj][i], x2 = acc[ti][tj + 2][i];
                    float c1 = cosb[s * 64 + d],      s1 = sinb[s * 64 + d];
                    float c2 = cosb[s * 64 + d + 32], s2 = sinb[s * 64 + d + 32];
                    dst[ob + d]      = f2bf((x1 * c1 - x2 * s1) * scl);
                    dst[ob + d + 32] = f2bf((x2 * c2 + x1 * s2) * scl);
                }
            }
    } else {
        int vcol = col0 - 2048;
#pragma unroll
        for (int ti = 0; ti < 4; ++ti)
#pragma unroll
            for (int tj = 0; tj < 4; ++tj)
#pragma unroll
                for (int i = 0; i < 4; ++i)
                    Vb[((size_t)(e * 1024) + sb + ti * 16 + i) * 1024 + vcol + tj * 16 + c] = f2bf(acc[ti][tj][i]);
    }
}

// ---------------- Wgu GEMM (interleaved columns) + fused SiLU*up epilogue ----------------
__global__ __launch_bounds__(256) void gemm_wgu_silu(const u16* __restrict__ Abase,
                                                     const u16* __restrict__ Wtbase,
                                                     u16* __restrict__ act,
                                                     const int* __restrict__ flat_idx) {
    __shared__ __align__(16) u16 As[128 * 64];
    __shared__ __align__(16) u16 Bs[128 * 64];
    const int K = 1024, N = 1536;
    int e = blockIdx.z;
    const u16* A  = Abase + (size_t)e * 1024 * K;
    const u16* Wt = Wtbase + (size_t)flat_idx[e] * N * K;
    int m0 = blockIdx.y * 128, n0 = blockIdx.x * 128;
    int t = threadIdx.x, lane = t & 63, w = t >> 6;
    int g = lane >> 4, c = lane & 15;
    int wm = (w >> 1) * 64, wn = (w & 1) * 64;

    GEMM_CORE64(A, Wt, K)

    int col0 = n0 + wn;
    int oc0 = (col0 >> 1) + c;          // act col for tj pair (0,1); +16 for (2,3)
    int sb = m0 + wm + g * 4;
#pragma unroll
    for (int ti = 0; ti < 4; ++ti)
#pragma unroll
        for (int i = 0; i < 4; ++i) {
            size_t rb = ((size_t)(e * 1024) + sb + ti * 16 + i) * 768;
#pragma unroll
            for (int pr = 0; pr < 2; ++pr) {
                float gt = acc[ti][pr * 2][i];
                float up = acc[ti][pr * 2 + 1][i];
                act[rb + oc0 + pr * 16] = f2bf(gt / (1.f + __expf(-gt)) * up);
            }
        }
}

// ---------------- V transpose: Vb[e][s][d] -> Vtg[e][h][d=64][kv=1024] ----------------
__global__ __launch_bounds__(256) void vtrans(const u16* __restrict__ Vb, u16* __restrict__ Vtg) {
    __shared__ __align__(16) u16 tile[64 * 72];
    int s0 = blockIdx.x * 64;
    int eh = blockIdx.y;
    int e = eh >> 4, h = eh & 15;
    int t = threadIdx.x;
#pragma unroll
    for (int it = 0; it < 2; ++it) {
        int p = it * 256 + t;
        int sr = p >> 3, ds = p & 7;
        u16x8 v = *(const u16x8*)&Vb[((size_t)(e * 1024) + s0 + sr) * 1024 + h * 64 + ds * 8];
        *(u16x8*)&tile[sr * 72 + ds * 8] = v;
    }
    __syncthreads();
#pragma unroll
    for (int it = 0; it < 2; ++it) {
        int p = it * 256 + t;
        int d = p >> 3, ks = p & 7;
        u16x8 o;
#pragma unroll
        for (int jj = 0; jj < 8; ++jj) o[jj] = tile[(ks * 8 + jj) * 72 + d];
        *(u16x8*)&Vtg[((size_t)((e * 16 + h) * 64) + d) * 1024 + s0 + ks * 8] = o;
    }
}

// ---------------- MFMA flash attention, 128 q-rows/block (2 q-subtiles/wave) ----------------
// 2x MFMA work per staged K/V tile vs round 0-2; halves K/V L2 streaming.
// 2-buffer counted-vmcnt staging retained from round 2 (4 loads/thread/tile, vmcnt(4)).
#define ATTN_STAGE(ktv, bo)                                                                 \
    {                                                                                       \
        _Pragma("unroll") for (int it = 0; it < 2; ++it) {                                  \
            GLDS16(gK[it] + (size_t)(ktv) * 64 * 1024, Ks + (bo) + (size_t)(it * 256 + w * 64) * 8); \
            GLDS16(gV[it] + (size_t)(ktv) * 64,        Vt + (bo) + (size_t)(it * 256 + w * 64) * 8); \
        }                                                                                   \
    }

__global__ __launch_bounds__(256) void attn_mfma(const u16* __restrict__ Qb, const u16* __restrict__ Kb,
                                                 const u16* __restrict__ Vtg, u16* __restrict__ ctx) {
    __shared__ __align__(16) u16 Ks[2 * 64 * 64];
    __shared__ __align__(16) u16 Vt[2 * 64 * 64];
    int e = blockIdx.x, h = blockIdx.y, qt = blockIdx.z;   // qt 0..7
    int t = threadIdx.x, lane = t & 63, w = t >> 6;
    int g = lane >> 4, c = lane & 15;
    int q0 = qt * 128 + w * 16;

    s8v qf[2][2];
#pragma unroll
    for (int qs = 0; qs < 2; ++qs)
#pragma unroll
        for (int ks = 0; ks < 2; ++ks)
            qf[qs][ks] = *(const s8v*)&Qb[((size_t)(e * 1024) + q0 + qs * 64 + c) * 1024 + h * 64 + ks * 32 + g * 8];

    f4v O[2][4];
    f4v li[2];
#pragma unroll
    for (int qs = 0; qs < 2; ++qs) {
        li[qs] = (f4v){0.f, 0.f, 0.f, 0.f};
#pragma unroll
        for (int tj = 0; tj < 4; ++tj) O[qs][tj] = (f4v){0.f, 0.f, 0.f, 0.f};
    }
    const s4v vone = {(short)0x3F80, (short)0x3F80, (short)0x3F80, (short)0x3F80};

    const u16* gK[2]; const u16* gV[2];
#pragma unroll
    for (int it = 0; it < 2; ++it) {
        int p = it * 256 + t;
        int row = p >> 3, ss = p & 7;
        gK[it] = Kb + ((size_t)(e * 1024 + row)) * 1024 + h * 64 + ((ss ^ (row & 7)) * 8);
        gV[it] = Vtg + ((size_t)((e * 16 + h) * 64 + row)) * 1024 + ((ss ^ (row & 7)) * 8);
    }

    ATTN_STAGE(0, 0)
    ATTN_STAGE(1, 4096)
    asm volatile("s_waitcnt vmcnt(4)" ::: "memory");
    BARRIER();
    int cb = 0;

    for (int kt = 0; kt < 16; ++kt) {
        int bo = cb * 4096;
#pragma unroll
        for (int qs = 0; qs < 2; ++qs) {
            f4v st[4];
#pragma unroll
            for (int tj = 0; tj < 4; ++tj) st[tj] = (f4v){0.f, 0.f, 0.f, 0.f};
#pragma unroll
            for (int ks = 0; ks < 2; ++ks)
#pragma unroll
                for (int tj = 0; tj < 4; ++tj) {
                    int kvl = tj * 16 + c;
                    s8v kf = *(const s8v*)&Ks[bo + kvl * 64 + (((ks * 4 + g) ^ (kvl & 7)) * 8)];
                    st[tj] = __builtin_amdgcn_mfma_f32_16x16x32_bf16(kf, qf[qs][ks], st[tj], 0, 0, 0);
                }

            s4v pf[4];
#pragma unroll
            for (int tj = 0; tj < 4; ++tj) {
                float p0 = __builtin_amdgcn_exp2f(st[tj][0]);
                float p1 = __builtin_amdgcn_exp2f(st[tj][1]);
                float p2 = __builtin_amdgcn_exp2f(st[tj][2]);
                float p3 = __builtin_amdgcn_exp2f(st[tj][3]);
                union { unsigned u[2]; s4v v; } pu;
                pu.u[0] = pk2(p0, p1);
                pu.u[1] = pk2(p2, p3);
                pf[tj] = pu.v;
            }

#pragma unroll
            for (int tjC = 0; tjC < 4; ++tjC) {
                li[qs] = __builtin_amdgcn_mfma_f32_16x16x16bf16_1k(pf[tjC], vone, li[qs], 0, 0, 0);
#pragma unroll
                for (int tjd = 0; tjd < 4; ++tjd) {
                    int d = tjd * 16 + c;
                    int sd = tjC * 2 + (g >> 1);
                    s4v vf = *(const s4v*)&Vt[bo + d * 64 + ((sd ^ (d & 7)) * 8) + (g & 1) * 4];
                    O[qs][tjd] = __builtin_amdgcn_mfma_f32_16x16x16bf16_1k(pf[tjC], vf, O[qs][tjd], 0, 0, 0);
                }
            }
        }

        BARRIER();
        if (kt + 2 < 16) {
            ATTN_STAGE(kt + 2, bo)
            asm volatile("s_waitcnt vmcnt(4)" ::: "memory");
        } else {
            asm volatile("s_waitcnt vmcnt(0)" ::: "memory");
        }
        BARRIER();
        cb ^= 1;
    }
#pragma unroll
    for (int qs = 0; qs < 2; ++qs)
#pragma unroll
        for (int i = 0; i < 4; ++i) {
            float linv = 1.0f / li[qs][i];
            size_t rbase = ((size_t)(e * 1024) + q0 + qs * 64 + g * 4 + i) * 1024 + h * 64;
#pragma unroll
            for (int tjd = 0; tjd < 4; ++tjd)
                ctx[rbase + tjd * 16 + c] = f2bf(O[qs][tjd][i] * linv);
        }
}

// ---------------- xnb = bf16(rmsnorm(hb[b] + aob)) ----------------
__global__ void add_rmsnorm(const u16* __restrict__ hb, const u16* __restrict__ aob,
                            u16* __restrict__ xnb) {
    int row = blockIdx.x;          // e*SEQ + s
    int e = row >> 10;
    int b = e >> 1;
    int s = row & 1023;
    const u16* xr = hb + (((size_t)b * SEQ_ + s) << 10);
    const u16* ar = aob + ((size_t)row << 10);
    u16* o = xnb + ((size_t)row << 10);
    int t = threadIdx.x;
    u16x4 xv = *(const u16x4*)&xr[t * 4];
    u16x4 av = *(const u16x4*)&ar[t * 4];
    float v[4];
    float ss = 0.f;
#pragma unroll
    for (int i = 0; i < 4; ++i) {
        v[i] = bf2f(xv[i]) + bf2f(av[i]);
        ss += v[i] * v[i];
    }
    for (int off = 32; off >= 1; off >>= 1) ss += __shfl_down(ss, off, 64);
    __shared__ float wred[4];
    if ((t & 63) == 0) wred[t >> 6] = ss;
    __syncthreads();
    float tot = wred[0] + wred[1] + wred[2] + wred[3];
    float scale = rsqrtf(tot * (1.0f / 1024.0f) + EPS_);
    u16x4 ov;
#pragma unroll
    for (int i = 0; i < 4; ++i) ov[i] = f2bf(v[i] * scale);
    *(u16x4*)&o[t * 4] = ov;
}

// ---------------- out[b] = sum_j w_e * rmsnorm(xn[e] + mlp[e]) ----------------
__global__ void final_kernel(const u16* __restrict__ xnb, const u16* __restrict__ mlpb,
                             const float* __restrict__ flat_w, float* __restrict__ out) {
    int row = blockIdx.x;           // b*SEQ + s
    int b = row >> 10;
    int s = row & 1023;
    int t = threadIdx.x;
    __shared__ float wred[4];
    float res[4] = {0.f, 0.f, 0.f, 0.f};
    for (int j = 0; j < 2; ++j) {
        int e = 2 * b + j;
        size_t off = (((size_t)e * SEQ_ + s) << 10);
        u16x4 xv = *(const u16x4*)&xnb[off + t * 4];
        u16x4 mv = *(const u16x4*)&mlpb[off + t * 4];
        float v[4];
        float ss = 0.f;
#pragma unroll
        for (int i = 0; i < 4; ++i) {
            v[i] = bf2f(xv[i]) + bf2f(mv[i]);
            ss += v[i] * v[i];
        }
        for (int off2 = 32; off2 >= 1; off2 >>= 1) ss += __shfl_down(ss, off2, 64);
        if ((t & 63) == 0) wred[t >> 6] = ss;
        __syncthreads();
        float tot = wred[0] + wred[1] + wred[2] + wred[3];
        float scale = rsqrtf(tot * (1.0f / 1024.0f) + EPS_);
        float wgt = flat_w[e];
#pragma unroll
        for (int i = 0; i < 4; ++i) res[i] += wgt * v[i] * scale;
        __syncthreads();
    }
    float* o = out + ((size_t)row << 10);
    *(float4*)&o[t * 4] = make_float4(res[0], res[1], res[2], res[3]);
}

extern "C" void kernel_launch(void* const* d_in, const int* in_sizes, int n_in,
                              void* d_out, int out_size, void* d_ws, size_t ws_size,
                              hipStream_t stream) {
    const float* hidden = (const float*)d_in[0];
    const float* cosb   = (const float*)d_in[1];
    const float* sinb   = (const float*)d_in[2];
    const float* Wr     = (const float*)d_in[3];
    const float* temp   = (const float*)d_in[4];
    const float* Wqkv   = (const float*)d_in[5];
    const float* Wo     = (const float*)d_in[6];
    const float* Wgu    = (const float*)d_in[7];
    const float* Wd     = (const float*)d_in[8];
    float* out = (float*)d_out;
    float* out_logits = out + (size_t)B_ * SEQ_ * D_;

    char* base = (char*)d_ws;
    int*   flat_idx = (int*)base;
    float* flat_w   = (float*)(base + 128);
    float* routeP   = (float*)(base + 4096);          // 512 KB
    size_t off = (size_t)1 << 20;
    u16* WqkvT = (u16*)(base + off); off += (size_t)8 * 3072 * 1024 * 2;
    u16* WoT   = (u16*)(base + off); off += (size_t)8 * 1024 * 1024 * 2;
    u16* WguT  = (u16*)(base + off); off += (size_t)8 * 1536 * 1024 * 2;
    u16* WdT   = (u16*)(base + off); off += (size_t)8 * 1024 * 768 * 2;
    u16* hb    = (u16*)(base + off); off += (size_t)4 * 1024 * 1024 * 2;
    u16* Qb    = (u16*)(base + off); off += (size_t)8 * 1024 * 1024 * 2;
    u16* Kb    = (u16*)(base + off); off += (size_t)8 * 1024 * 1024 * 2;
    u16* Vb    = (u16*)(base + off); off += (size_t)8 * 1024 * 1024 * 2;
    u16* Vtg   = (u16*)(base + off); off += (size_t)8 * 1024 * 1024 * 2;
    u16* ctxb  = (u16*)(base + off); off += (size_t)8 * 1024 * 1024 * 2;
    u16* aob   = (u16*)(base + off); off += (size_t)8 * 1024 * 1024 * 2;
    u16* xnb   = (u16*)(base + off); off += (size_t)8 * 1024 * 1024 * 2;
    u16* actb  = (u16*)(base + off); off += (size_t)8 * 1024 * 768 * 2;
    u16* mlpb  = (u16*)(base + off); off += (size_t)8 * 1024 * 1024 * 2;

    route1<<<dim3(4, 32), 256, 0, stream>>>(hidden, routeP, hb);
    route2<<<4, 256, 0, stream>>>(routeP, Wr, temp, out_logits, flat_idx, flat_w);
    wtrans_all<<<12800, 256, 0, stream>>>(Wqkv, Wo, Wgu, Wd, WqkvT, WoT, WguT, WdT, flat_idx);

    gemm_qkv<<<dim3(24, 8, 8), 256, 0, stream>>>(hb, WqkvT, flat_idx, cosb, sinb, Qb, Kb, Vb);
    vtrans<<<dim3(16, 128), 256, 0, stream>>>(Vb, Vtg);
    attn_mfma<<<dim3(8, 16, 8), 256, 0, stream>>>(Qb, Kb, Vtg, ctxb);
    gemm_bf16<<<dim3(8, 8, 8), 256, 0, stream>>>(ctxb, WoT, aob, flat_idx, 1024, 1024, 1024, 1);
    add_rmsnorm<<<NE_ * SEQ_, 256, 0, stream>>>(hb, aob, xnb);
    gemm_wgu_silu<<<dim3(12, 8, 8), 256, 0, stream>>>(xnb, WguT, actb, flat_idx);
    gemm_bf16<<<dim3(8, 8, 8), 256, 0, stream>>>(actb, WdT, mlpb, flat_idx, 1024, 1024, 768, 1);
    final_kernel<<<B_ * SEQ_, 256, 0, stream>>>(xnb, mlpb, flat_w, out);
}